// Round 2
// baseline (737.320 us; speedup 1.0000x reference)
//
#include <hip/hip_runtime.h>

#define NTOK 4096
#define NEXP 8
#define HD 2048
#define ID 1408

typedef unsigned short u16;
typedef __attribute__((ext_vector_type(8))) short short8;
typedef __attribute__((ext_vector_type(4))) short short4v;
typedef __attribute__((ext_vector_type(4))) float f32x4;
typedef const __attribute__((address_space(1))) void* gas_ptr;
typedef __attribute__((address_space(3))) void* las_ptr;

__device__ __forceinline__ u16 f2bf(float f) {
  unsigned int u = __float_as_uint(f);
  u += 0x7FFFu + ((u >> 16) & 1u);   // RNE
  return (u16)(u >> 16);
}

__device__ __forceinline__ void async16(const u16* g, u16* l) {
  __builtin_amdgcn_global_load_lds((gas_ptr)g, (las_ptr)l, 16, 0, 0);
}

// fp32 -> bf16 bulk convert, 8 elems/thread (weights only; x is converted in router)
__global__ void cvt_kernel(const float* __restrict__ s, u16* __restrict__ d, long n8) {
  long i = (long)blockIdx.x * blockDim.x + threadIdx.x;
  if (i >= n8) return;
  const float4* s4 = (const float4*)s;
  float4 a = s4[2*i], b = s4[2*i+1];
  short8 o;
  o[0] = (short)f2bf(a.x); o[1] = (short)f2bf(a.y);
  o[2] = (short)f2bf(a.z); o[3] = (short)f2bf(a.w);
  o[4] = (short)f2bf(b.x); o[5] = (short)f2bf(b.y);
  o[6] = (short)f2bf(b.z); o[7] = (short)f2bf(b.w);
  *(short8*)(d + 8*i) = o;
}

// router: logits (fp32), softmax, top-2, per-expert scatter lists.
// Also converts x -> bf16 (xb) on the way through (x is fully read here anyway).
__global__ void router_kernel(const float* __restrict__ x, const float* __restrict__ gw,
                              u16* __restrict__ xb,
                              float* __restrict__ logits, int* __restrict__ cnt,
                              int* __restrict__ ptok, float* __restrict__ pw) {
  int t = blockIdx.x * 4 + (threadIdx.x >> 6);   // one wave per token
  int lane = threadIdx.x & 63;
  if (t >= NTOK) return;
  const float4* xr = (const float4*)(x + (size_t)t * HD);
  u16* xbr = xb + (size_t)t * HD;
  float dot[NEXP];
#pragma unroll
  for (int e = 0; e < NEXP; ++e) dot[e] = 0.f;
#pragma unroll
  for (int c = 0; c < 8; ++c) {                  // 2048/4/64 = 8 chunks
    float4 xv = xr[c*64 + lane];
    // fused x -> bf16 store
    short4v o;
    o[0] = (short)f2bf(xv.x); o[1] = (short)f2bf(xv.y);
    o[2] = (short)f2bf(xv.z); o[3] = (short)f2bf(xv.w);
    *(short4v*)(xbr + (c*64 + lane)*4) = o;
#pragma unroll
    for (int e = 0; e < NEXP; ++e) {
      float4 gv = ((const float4*)(gw + e*HD))[c*64 + lane];
      dot[e] += xv.x*gv.x + xv.y*gv.y + xv.z*gv.z + xv.w*gv.w;
    }
  }
#pragma unroll
  for (int off = 32; off > 0; off >>= 1) {
#pragma unroll
    for (int e = 0; e < NEXP; ++e) dot[e] += __shfl_xor(dot[e], off);
  }
  if (lane < NEXP) logits[(size_t)t*NEXP + lane] = dot[lane];
  if (lane == 0) {
    float mx = dot[0];
#pragma unroll
    for (int e = 1; e < NEXP; ++e) mx = fmaxf(mx, dot[e]);
    float p[NEXP];
#pragma unroll
    for (int e = 0; e < NEXP; ++e) p[e] = __expf(dot[e] - mx);
    int e0 = 0;
#pragma unroll
    for (int e = 1; e < NEXP; ++e) if (p[e] > p[e0]) e0 = e;   // ties -> lowest idx
    int e1 = (e0 == 0) ? 1 : 0;
#pragma unroll
    for (int e = 0; e < NEXP; ++e) if (e != e0 && p[e] > p[e1]) e1 = e;
    float denom = p[e0] + p[e1];
    int pos0 = atomicAdd(&cnt[e0], 1);
    ptok[e0*NTOK + pos0] = t; pw[e0*NTOK + pos0] = p[e0] / denom;
    int pos1 = atomicAdd(&cnt[e1], 1);
    ptok[e1*NTOK + pos1] = t; pw[e1*NTOK + pos1] = p[e1] / denom;
  }
}

__global__ void prefix_kernel(const int* __restrict__ cnt, int* __restrict__ offs) {
  if (threadIdx.x == 0) {
    int a = 0;
    for (int e = 0; e < NEXP; ++e) { offs[e] = a; a += cnt[e]; }
  }
}

// GEMM1: per expert, h = silu(x@wg^T) * (x@wu^T), rows gathered via ptok, h stored bf16.
// Double-buffered LDS (prefetch next K-tile before computing current; ONE barrier per
// K-step, so the global_load_lds flight overlaps the MFMA phase).
// Grid flattened 1D with XCD-aware swizzle: the 11 nt-blocks sharing an A-tile (one
// (e,mt) group) land on the same XCD; groups round-robin over XCDs for load balance.
__global__ __launch_bounds__(256, 2) void gemm1_kernel(
    const u16* __restrict__ xb, const u16* __restrict__ wgb, const u16* __restrict__ wub,
    const int* __restrict__ cnt, const int* __restrict__ offs,
    const int* __restrict__ ptok, u16* __restrict__ hbuf) {
  // 2816 blocks = 8 xcd * 32 groups/xcd * 11 nt
  int b = blockIdx.x;
  int xcd = b & 7;
  int j = b >> 3;                 // 0..351 within XCD
  int gidx = j / 11, nt = j % 11; // group slot, nt fastest -> A-tile reuse in L2
  int g = gidx * 8 + xcd;         // group id 0..255  (round-robin over XCDs)
  int e = g >> 5, mt = g & 31;
  int c = cnt[e];
  if (mt * 128 >= c) return;
  int off = offs[e];

  __shared__ u16 sA[2][128*32], sBg[2][128*32], sBu[2][128*32];

  int tid = threadIdx.x;
  int r0 = tid >> 2;
  int ch = (tid & 3) * 8;
  int s0 = mt*128 + r0, s1 = s0 + 64;
  int t0 = ptok[e*NTOK + (s0 < c ? s0 : 0)];
  int t1 = ptok[e*NTOK + (s1 < c ? s1 : 0)];
  const u16* ga0 = xb + (size_t)t0*HD + ch;
  const u16* ga1 = xb + (size_t)t1*HD + ch;
  int n0 = nt*128 + r0;
  const u16* gg0 = wgb + ((size_t)e*ID + n0)*HD + ch;
  const u16* gg1 = gg0 + (size_t)64*HD;
  const u16* gu0 = wub + ((size_t)e*ID + n0)*HD + ch;
  const u16* gu1 = gu0 + (size_t)64*HD;

  int lane = tid & 63, wv = tid >> 6, wr = wv >> 1, wc = wv & 1;
  int fm = lane & 15, kg = lane >> 4;

  f32x4 accg[4][4], accu[4][4];
#pragma unroll
  for (int i = 0; i < 4; ++i)
#pragma unroll
    for (int jj = 0; jj < 4; ++jj) {
      accg[i][jj] = {0.f, 0.f, 0.f, 0.f};
      accu[i][jj] = {0.f, 0.f, 0.f, 0.f};
    }

  const int aoff = (wr*64 + fm)*32 + kg*8;
  const int boff = (wc*64 + fm)*32 + kg*8;

#define STAGE1(buf, k0) do { \
    async16(ga0 + (k0), sA[buf] + tid*8); \
    async16(ga1 + (k0), sA[buf] + 2048 + tid*8); \
    async16(gg0 + (k0), sBg[buf] + tid*8); \
    async16(gg1 + (k0), sBg[buf] + 2048 + tid*8); \
    async16(gu0 + (k0), sBu[buf] + tid*8); \
    async16(gu1 + (k0), sBu[buf] + 2048 + tid*8); \
  } while (0)

  STAGE1(0, 0);
  __syncthreads();
  int cur = 0;
  for (int k0 = 0; k0 < HD; k0 += 32) {
    int nk = k0 + 32;
    if (nk < HD) STAGE1(cur ^ 1, nk);   // prefetch stays in flight across the MFMAs
    const u16* pa = sA[cur] + aoff;
    const u16* pg = sBg[cur] + boff;
    const u16* pu = sBu[cur] + boff;
    short8 af[4], bg[4], bu[4];
#pragma unroll
    for (int i = 0; i < 4; ++i) af[i] = *(const short8*)(pa + i*512);
#pragma unroll
    for (int jj = 0; jj < 4; ++jj) {
      bg[jj] = *(const short8*)(pg + jj*512);
      bu[jj] = *(const short8*)(pu + jj*512);
    }
#pragma unroll
    for (int i = 0; i < 4; ++i)
#pragma unroll
      for (int jj = 0; jj < 4; ++jj) {
        accg[i][jj] = __builtin_amdgcn_mfma_f32_16x16x32_bf16(af[i], bg[jj], accg[i][jj], 0, 0, 0);
        accu[i][jj] = __builtin_amdgcn_mfma_f32_16x16x32_bf16(af[i], bu[jj], accu[i][jj], 0, 0, 0);
      }
    __syncthreads();   // drains prefetch vmcnt (overlapped with compute above) + swap safety
    cur ^= 1;
  }
#undef STAGE1

#pragma unroll
  for (int i = 0; i < 4; ++i) {
#pragma unroll
    for (int r = 0; r < 4; ++r) {
      int slot = mt*128 + wr*64 + i*16 + kg*4 + r;
      if (slot < c) {
        size_t rowb = (size_t)(off + slot) * ID + nt*128 + wc*64 + fm;
#pragma unroll
        for (int jj = 0; jj < 4; ++jj) {
          float gg = accg[i][jj][r], uu = accu[i][jj][r];
          float hh = gg * uu / (1.f + __expf(-gg));   // silu(g)*u
          hbuf[rowb + (size_t)jj*16] = f2bf(hh);
        }
      }
    }
  }
}

// GEMM2: y = h @ wd^T, weighted atomic scatter into out. Same dbuf + XCD swizzle.
__global__ __launch_bounds__(256, 2) void gemm2_kernel(
    const u16* __restrict__ hbuf, const u16* __restrict__ wdb,
    const int* __restrict__ cnt, const int* __restrict__ offs,
    const int* __restrict__ ptok, const float* __restrict__ pw,
    float* __restrict__ out) {
  // 4096 blocks = 8 xcd * 32 groups/xcd * 16 nt
  int b = blockIdx.x;
  int xcd = b & 7;
  int j = b >> 3;                  // 0..511
  int gidx = j >> 4, nt = j & 15;
  int g = gidx * 8 + xcd;
  int e = g >> 5, mt = g & 31;
  int c = cnt[e];
  if (mt * 128 >= c) return;
  int off = offs[e];

  __shared__ u16 sA[2][128*32], sB[2][128*32];

  int tid = threadIdx.x;
  int r0 = tid >> 2;
  int ch = (tid & 3) * 8;
  int s0 = mt*128 + r0, s1 = s0 + 64;
  const u16* ga0 = hbuf + (size_t)(off + (s0 < c ? s0 : 0))*ID + ch;
  const u16* ga1 = hbuf + (size_t)(off + (s1 < c ? s1 : 0))*ID + ch;
  int n0 = nt*128 + r0;
  const u16* gb0 = wdb + ((size_t)e*HD + n0)*ID + ch;
  const u16* gb1 = gb0 + (size_t)64*ID;

  int lane = tid & 63, wv = tid >> 6, wr = wv >> 1, wc = wv & 1;
  int fm = lane & 15, kg = lane >> 4;

  f32x4 acc[4][4];
#pragma unroll
  for (int i = 0; i < 4; ++i)
#pragma unroll
    for (int jj = 0; jj < 4; ++jj) acc[i][jj] = {0.f, 0.f, 0.f, 0.f};

  const int aoff = (wr*64 + fm)*32 + kg*8;
  const int boff = (wc*64 + fm)*32 + kg*8;

#define STAGE2(buf, k0) do { \
    async16(ga0 + (k0), sA[buf] + tid*8); \
    async16(ga1 + (k0), sA[buf] + 2048 + tid*8); \
    async16(gb0 + (k0), sB[buf] + tid*8); \
    async16(gb1 + (k0), sB[buf] + 2048 + tid*8); \
  } while (0)

  STAGE2(0, 0);
  __syncthreads();
  int cur = 0;
  for (int k0 = 0; k0 < ID; k0 += 32) {
    int nk = k0 + 32;
    if (nk < ID) STAGE2(cur ^ 1, nk);
    const u16* pa = sA[cur] + aoff;
    const u16* pb = sB[cur] + boff;
    short8 af[4], bf[4];
#pragma unroll
    for (int i = 0; i < 4; ++i) af[i] = *(const short8*)(pa + i*512);
#pragma unroll
    for (int jj = 0; jj < 4; ++jj) bf[jj] = *(const short8*)(pb + jj*512);
#pragma unroll
    for (int i = 0; i < 4; ++i)
#pragma unroll
      for (int jj = 0; jj < 4; ++jj)
        acc[i][jj] = __builtin_amdgcn_mfma_f32_16x16x32_bf16(af[i], bf[jj], acc[i][jj], 0, 0, 0);
    __syncthreads();
    cur ^= 1;
  }
#undef STAGE2

#pragma unroll
  for (int i = 0; i < 4; ++i) {
#pragma unroll
    for (int r = 0; r < 4; ++r) {
      int slot = mt*128 + wr*64 + i*16 + kg*4 + r;
      if (slot < c) {
        int tok = ptok[e*NTOK + slot];
        float wgt = pw[e*NTOK + slot];
        float* orow = out + (size_t)tok*HD + nt*128 + wc*64 + fm;
#pragma unroll
        for (int jj = 0; jj < 4; ++jj)
          atomicAdd(orow + jj*16, wgt * acc[i][jj][r]);
      }
    }
  }
}

extern "C" void kernel_launch(void* const* d_in, const int* in_sizes, int n_in,
                              void* d_out, int out_size, void* d_ws, size_t ws_size,
                              hipStream_t stream) {
  const float* x  = (const float*)d_in[0];
  const float* gw = (const float*)d_in[1];
  const float* wg = (const float*)d_in[2];
  const float* wu = (const float*)d_in[3];
  const float* wd = (const float*)d_in[4];
  float* out = (float*)d_out;

  // workspace carve (bytes), all 16B-aligned
  char* p = (char*)d_ws;
  u16*   xb   = (u16*)(p);                    //  16,777,216 B : x bf16 [4096,2048]
  u16*   wgb  = (u16*)(p + 16777216UL);       //  46,137,344 B : wg bf16
  u16*   wub  = (u16*)(p + 62914560UL);       //  46,137,344 B : wu bf16
  u16*   wdb  = (u16*)(p + 109051904UL);      //  46,137,344 B : wd bf16
  u16*   hbuf = (u16*)(p + 155189248UL);      //  23,068,672 B : h bf16 [8192,1408]
  int*   ptok = (int*)(p + 178257920UL);      //     131,072 B
  float* pww  = (float*)(p + 178388992UL);    //     131,072 B
  int*   cnt  = (int*)(p + 178520064UL);      //         256 B
  int*   offs = (int*)(p + 178520320UL);      //         256 B

  hipMemsetAsync(out, 0, (size_t)NTOK * HD * sizeof(float), stream);
  hipMemsetAsync(cnt, 0, NEXP * sizeof(int), stream);

  cvt_kernel<<<11264, 256, 0, stream>>>(wg, wgb, (long)NEXP * ID * HD / 8);
  cvt_kernel<<<11264, 256, 0, stream>>>(wu, wub, (long)NEXP * ID * HD / 8);
  cvt_kernel<<<11264, 256, 0, stream>>>(wd, wdb, (long)NEXP * HD * ID / 8);

  router_kernel<<<1024, 256, 0, stream>>>(x, gw, xb, out + (size_t)NTOK * HD, cnt, ptok, pww);
  prefix_kernel<<<1, 64, 0, stream>>>(cnt, offs);

  gemm1_kernel<<<2816, 256, 0, stream>>>(xb, wgb, wub, cnt, offs, ptok, hbuf);
  gemm2_kernel<<<4096, 256, 0, stream>>>(hbuf, wdb, cnt, offs, ptok, pww, out);
}

// Round 3
// 652.276 us; speedup vs baseline: 1.1304x; 1.1304x over previous
//
#include <hip/hip_runtime.h>

#define NTOK 4096
#define NEXP 8
#define HD 2048
#define ID 1408

typedef unsigned short u16;
typedef __attribute__((ext_vector_type(8))) short short8;
typedef __attribute__((ext_vector_type(4))) short short4v;
typedef __attribute__((ext_vector_type(4))) float f32x4;
typedef const __attribute__((address_space(1))) void* gas_ptr;
typedef __attribute__((address_space(3))) void* las_ptr;

__device__ __forceinline__ u16 f2bf(float f) {
  unsigned int u = __float_as_uint(f);
  u += 0x7FFFu + ((u >> 16) & 1u);   // RNE
  return (u16)(u >> 16);
}

__device__ __forceinline__ void async16(const u16* g, u16* l) {
  __builtin_amdgcn_global_load_lds((gas_ptr)g, (las_ptr)l, 16, 0, 0);
}

// fp32 -> bf16 bulk convert for the 3 weight tensors in one launch.
__global__ void cvt3_kernel(const float* __restrict__ s0, const float* __restrict__ s1,
                            const float* __restrict__ s2, u16* __restrict__ d0,
                            u16* __restrict__ d1, u16* __restrict__ d2, long n8each) {
  long i = (long)blockIdx.x * blockDim.x + threadIdx.x;
  const float* s; u16* d; long j;
  if (i < n8each)            { s = s0; d = d0; j = i; }
  else if (i < 2*n8each)     { s = s1; d = d1; j = i - n8each; }
  else if (i < 3*n8each)     { s = s2; d = d2; j = i - 2*n8each; }
  else return;
  const float4* s4 = (const float4*)s;
  float4 a = s4[2*j], b = s4[2*j+1];
  short8 o;
  o[0] = (short)f2bf(a.x); o[1] = (short)f2bf(a.y);
  o[2] = (short)f2bf(a.z); o[3] = (short)f2bf(a.w);
  o[4] = (short)f2bf(b.x); o[5] = (short)f2bf(b.y);
  o[6] = (short)f2bf(b.z); o[7] = (short)f2bf(b.w);
  *(short8*)(d + 8*j) = o;
}

// router: logits (fp32), softmax, top-2, per-expert scatter lists.
// Also converts x -> bf16 (xb) on the way through (x is fully read here anyway).
__global__ void router_kernel(const float* __restrict__ x, const float* __restrict__ gw,
                              u16* __restrict__ xb,
                              float* __restrict__ logits, int* __restrict__ cnt,
                              int* __restrict__ ptok, float* __restrict__ pw) {
  int t = blockIdx.x * 4 + (threadIdx.x >> 6);   // one wave per token
  int lane = threadIdx.x & 63;
  if (t >= NTOK) return;
  const float4* xr = (const float4*)(x + (size_t)t * HD);
  u16* xbr = xb + (size_t)t * HD;
  float dot[NEXP];
#pragma unroll
  for (int e = 0; e < NEXP; ++e) dot[e] = 0.f;
#pragma unroll
  for (int c = 0; c < 8; ++c) {                  // 2048/4/64 = 8 chunks
    float4 xv = xr[c*64 + lane];
    short4v o;
    o[0] = (short)f2bf(xv.x); o[1] = (short)f2bf(xv.y);
    o[2] = (short)f2bf(xv.z); o[3] = (short)f2bf(xv.w);
    *(short4v*)(xbr + (c*64 + lane)*4) = o;
#pragma unroll
    for (int e = 0; e < NEXP; ++e) {
      float4 gv = ((const float4*)(gw + e*HD))[c*64 + lane];
      dot[e] += xv.x*gv.x + xv.y*gv.y + xv.z*gv.z + xv.w*gv.w;
    }
  }
#pragma unroll
  for (int off = 32; off > 0; off >>= 1) {
#pragma unroll
    for (int e = 0; e < NEXP; ++e) dot[e] += __shfl_xor(dot[e], off);
  }
  if (lane < NEXP) logits[(size_t)t*NEXP + lane] = dot[lane];
  if (lane == 0) {
    float mx = dot[0];
#pragma unroll
    for (int e = 1; e < NEXP; ++e) mx = fmaxf(mx, dot[e]);
    float p[NEXP];
#pragma unroll
    for (int e = 0; e < NEXP; ++e) p[e] = __expf(dot[e] - mx);
    int e0 = 0;
#pragma unroll
    for (int e = 1; e < NEXP; ++e) if (p[e] > p[e0]) e0 = e;   // ties -> lowest idx
    int e1 = (e0 == 0) ? 1 : 0;
#pragma unroll
    for (int e = 0; e < NEXP; ++e) if (e != e0 && p[e] > p[e1]) e1 = e;
    float denom = p[e0] + p[e1];
    int pos0 = atomicAdd(&cnt[e0], 1);
    ptok[e0*NTOK + pos0] = t; pw[e0*NTOK + pos0] = p[e0] / denom;
    int pos1 = atomicAdd(&cnt[e1], 1);
    ptok[e1*NTOK + pos1] = t; pw[e1*NTOK + pos1] = p[e1] / denom;
  }
}

__global__ void prefix_kernel(const int* __restrict__ cnt, int* __restrict__ offs) {
  if (threadIdx.x == 0) {
    int a = 0;
    for (int e = 0; e < NEXP; ++e) { offs[e] = a; a += cnt[e]; }
  }
}

// GEMM1: h = silu(x@wg^T) * (x@wu^T) per expert, rows gathered via ptok, h stored bf16.
// BK=64, single-buffered LDS (halves barrier count vs BK=32).
// LDS tiles are [128 rows][64 elems] (128 B rows = 32 banks); reads are XOR-swizzled
// (chunk ^ (row&7)) to be bank-conflict-free, with the inverse swizzle applied to the
// GLOBAL source address at staging time so global_load_lds's linear LDS write is correct
// (rule: linear dest + inverse-swizzled source + swizzled read).
__global__ __launch_bounds__(256, 2) void gemm1_kernel(
    const u16* __restrict__ xb, const u16* __restrict__ wgb, const u16* __restrict__ wub,
    const int* __restrict__ cnt, const int* __restrict__ offs,
    const int* __restrict__ ptok, u16* __restrict__ hbuf) {
  int e = blockIdx.z, mt = blockIdx.y, nt = blockIdx.x;
  int c = cnt[e];
  if (mt * 128 >= c) return;
  int off = offs[e];

  __shared__ u16 sA[128*64], sBg[128*64], sBu[128*64];   // 3 x 16 KB

  int tid = threadIdx.x;
  int r  = tid >> 3;                 // staging row (within 32-row slab), 0..31
  int cq = tid & 7;                  // staging chunk 0..7 (16 B each)
  int cx = (cq ^ (r & 7)) * 8;       // inverse-swizzled global chunk (elems)

  // A rows mt*128 + r + p*32, token-gathered (same swizzle for all p: 32 % 8 == 0)
  const u16* ga[4];
#pragma unroll
  for (int p = 0; p < 4; ++p) {
    int s = mt*128 + r + p*32;
    int t = ptok[e*NTOK + (s < c ? s : 0)];
    ga[p] = xb + (size_t)t*HD + cx;
  }
  int n0 = nt*128 + r;
  const u16* gg = wgb + ((size_t)e*ID + n0)*HD + cx;
  const u16* gu = wub + ((size_t)e*ID + n0)*HD + cx;

  int lane = tid & 63, wv = tid >> 6, wr = wv >> 1, wc = wv & 1;
  int fm = lane & 15, kg = lane >> 4;
  int sw = fm & 7;                   // read-side swizzle (row&7 == fm&7 for all frag rows)

  f32x4 accg[4][4], accu[4][4];
#pragma unroll
  for (int i = 0; i < 4; ++i)
#pragma unroll
    for (int j = 0; j < 4; ++j) {
      accg[i][j] = {0.f, 0.f, 0.f, 0.f};
      accu[i][j] = {0.f, 0.f, 0.f, 0.f};
    }

  for (int k0 = 0; k0 < HD; k0 += 64) {
#pragma unroll
    for (int p = 0; p < 4; ++p) {
      async16(ga[p] + k0,                 sA  + p*2048 + tid*8);
      async16(gg + (size_t)p*32*HD + k0,  sBg + p*2048 + tid*8);
      async16(gu + (size_t)p*32*HD + k0,  sBu + p*2048 + tid*8);
    }
    __syncthreads();
#pragma unroll
    for (int h = 0; h < 2; ++h) {
      int co = ((kg + 4*h) ^ sw) * 8;    // swizzled read chunk for this K-half
      short8 af[4], bg[4], bu[4];
#pragma unroll
      for (int i = 0; i < 4; ++i)
        af[i] = *(const short8*)(sA + (wr*64 + i*16 + fm)*64 + co);
#pragma unroll
      for (int j = 0; j < 4; ++j) {
        bg[j] = *(const short8*)(sBg + (wc*64 + j*16 + fm)*64 + co);
        bu[j] = *(const short8*)(sBu + (wc*64 + j*16 + fm)*64 + co);
      }
#pragma unroll
      for (int i = 0; i < 4; ++i)
#pragma unroll
        for (int j = 0; j < 4; ++j) {
          accg[i][j] = __builtin_amdgcn_mfma_f32_16x16x32_bf16(af[i], bg[j], accg[i][j], 0, 0, 0);
          accu[i][j] = __builtin_amdgcn_mfma_f32_16x16x32_bf16(af[i], bu[j], accu[i][j], 0, 0, 0);
        }
    }
    __syncthreads();
  }

#pragma unroll
  for (int i = 0; i < 4; ++i) {
#pragma unroll
    for (int rr = 0; rr < 4; ++rr) {
      int slot = mt*128 + wr*64 + i*16 + kg*4 + rr;
      if (slot < c) {
        size_t rowb = (size_t)(off + slot) * ID + nt*128 + wc*64 + fm;
#pragma unroll
        for (int j = 0; j < 4; ++j) {
          float gv = accg[i][j][rr], uv = accu[i][j][rr];
          float hh = gv * uv / (1.f + __expf(-gv));   // silu(g)*u
          hbuf[rowb + (size_t)j*16] = f2bf(hh);
        }
      }
    }
  }
}

// GEMM2: y = h @ wd^T, weighted atomic scatter into out. BK=64, swizzled, single-buffer.
__global__ __launch_bounds__(256, 3) void gemm2_kernel(
    const u16* __restrict__ hbuf, const u16* __restrict__ wdb,
    const int* __restrict__ cnt, const int* __restrict__ offs,
    const int* __restrict__ ptok, const float* __restrict__ pw,
    float* __restrict__ out) {
  int e = blockIdx.z, mt = blockIdx.y, nt = blockIdx.x;
  int c = cnt[e];
  if (mt * 128 >= c) return;
  int off = offs[e];

  __shared__ u16 sA[128*64], sB[128*64];   // 2 x 16 KB

  int tid = threadIdx.x;
  int r  = tid >> 3;
  int cq = tid & 7;
  int cx = (cq ^ (r & 7)) * 8;

  const u16* ga[4];
#pragma unroll
  for (int p = 0; p < 4; ++p) {
    int s = mt*128 + r + p*32;
    ga[p] = hbuf + (size_t)(off + (s < c ? s : 0))*ID + cx;
  }
  int n0 = nt*128 + r;
  const u16* gb = wdb + ((size_t)e*HD + n0)*ID + cx;

  int lane = tid & 63, wv = tid >> 6, wr = wv >> 1, wc = wv & 1;
  int fm = lane & 15, kg = lane >> 4;
  int sw = fm & 7;

  f32x4 acc[4][4];
#pragma unroll
  for (int i = 0; i < 4; ++i)
#pragma unroll
    for (int j = 0; j < 4; ++j) acc[i][j] = {0.f, 0.f, 0.f, 0.f};

  for (int k0 = 0; k0 < ID; k0 += 64) {
#pragma unroll
    for (int p = 0; p < 4; ++p) {
      async16(ga[p] + k0,                sA + p*2048 + tid*8);
      async16(gb + (size_t)p*32*ID + k0, sB + p*2048 + tid*8);
    }
    __syncthreads();
#pragma unroll
    for (int h = 0; h < 2; ++h) {
      int co = ((kg + 4*h) ^ sw) * 8;
      short8 af[4], bf[4];
#pragma unroll
      for (int i = 0; i < 4; ++i)
        af[i] = *(const short8*)(sA + (wr*64 + i*16 + fm)*64 + co);
#pragma unroll
      for (int j = 0; j < 4; ++j)
        bf[j] = *(const short8*)(sB + (wc*64 + j*16 + fm)*64 + co);
#pragma unroll
      for (int i = 0; i < 4; ++i)
#pragma unroll
        for (int j = 0; j < 4; ++j)
          acc[i][j] = __builtin_amdgcn_mfma_f32_16x16x32_bf16(af[i], bf[j], acc[i][j], 0, 0, 0);
    }
    __syncthreads();
  }

#pragma unroll
  for (int i = 0; i < 4; ++i) {
#pragma unroll
    for (int rr = 0; rr < 4; ++rr) {
      int slot = mt*128 + wr*64 + i*16 + kg*4 + rr;
      if (slot < c) {
        int tok = ptok[e*NTOK + slot];
        float wgt = pw[e*NTOK + slot];
        float* orow = out + (size_t)tok*HD + nt*128 + wc*64 + fm;
#pragma unroll
        for (int j = 0; j < 4; ++j)
          atomicAdd(orow + j*16, wgt * acc[i][j][rr]);
      }
    }
  }
}

extern "C" void kernel_launch(void* const* d_in, const int* in_sizes, int n_in,
                              void* d_out, int out_size, void* d_ws, size_t ws_size,
                              hipStream_t stream) {
  const float* x  = (const float*)d_in[0];
  const float* gw = (const float*)d_in[1];
  const float* wg = (const float*)d_in[2];
  const float* wu = (const float*)d_in[3];
  const float* wd = (const float*)d_in[4];
  float* out = (float*)d_out;

  // workspace carve (bytes), all 16B-aligned
  char* p = (char*)d_ws;
  u16*   xb   = (u16*)(p);                    //  16,777,216 B : x bf16 [4096,2048]
  u16*   wgb  = (u16*)(p + 16777216UL);       //  46,137,344 B : wg bf16
  u16*   wub  = (u16*)(p + 62914560UL);       //  46,137,344 B : wu bf16
  u16*   wdb  = (u16*)(p + 109051904UL);      //  46,137,344 B : wd bf16
  u16*   hbuf = (u16*)(p + 155189248UL);      //  23,068,672 B : h bf16 [8192,1408]
  int*   ptok = (int*)(p + 178257920UL);      //     131,072 B
  float* pww  = (float*)(p + 178388992UL);    //     131,072 B
  int*   cnt  = (int*)(p + 178520064UL);      //         256 B
  int*   offs = (int*)(p + 178520320UL);      //         256 B

  hipMemsetAsync(out, 0, (size_t)NTOK * HD * sizeof(float), stream);
  hipMemsetAsync(cnt, 0, NEXP * sizeof(int), stream);

  long n8each = (long)NEXP * ID * HD / 8;     // 2,883,584
  cvt3_kernel<<<33792, 256, 0, stream>>>(wg, wu, wd, wgb, wub, wdb, n8each);

  router_kernel<<<1024, 256, 0, stream>>>(x, gw, xb, out + (size_t)NTOK * HD, cnt, ptok, pww);
  prefix_kernel<<<1, 64, 0, stream>>>(cnt, offs);

  gemm1_kernel<<<dim3(11, 32, 8), 256, 0, stream>>>(xb, wgb, wub, cnt, offs, ptok, hbuf);
  gemm2_kernel<<<dim3(16, 32, 8), 256, 0, stream>>>(hbuf, wdb, cnt, offs, ptok, pww, out);
}